// Round 7
// baseline (212.180 us; speedup 1.0000x reference)
//
#include <hip/hip_runtime.h>

// CountHistogram: B=64, C=4, Q=32, D=4096, NBINS=29
// out[b,c,q,bin] = sum_d mask[b,q,d] * (bin == trunc((simmat[b,c,q,d]+1.00001)/2*28))
//
// R6 = R5 with the nontemporal hint removed from the simmat stream (single-
// variable test). Rationale: R0/R2/R5 proved the LDS scheme is off the
// critical path (all within 1.5us); the only change that ever moved dur_us
// was R3 (NT + unroll8, -10.6us), and R4 showed NT-mask is neutral. Two live
// theories: (a) unroll8 was the real win and NT-simmat forfeits L3 hits on
// the 128 MiB simmat that the harness's restore-copy just wrote into the
// 256 MiB Infinity Cache -> cached loads should WIN; (b) NT-simmat was the
// win (L2 thrash avoidance) -> this regresses ~10us and I revert.
// Histogram: NCOPY=64, lane-private columns, plain ds_read+add+ds_write,
// zero atomics, bank=lane&31 -> 2 lanes/bank free tier (m136).

constexpr int Bdim  = 64;
constexpr int Cdim  = 4;
constexpr int Qdim  = 32;
constexpr int Ddim  = 4096;
constexpr int NBINS = 29;
constexpr int NCOPY = 64;                 // one private column per lane
constexpr int WHIST = NBINS * NCOPY;      // 1856 words per wave

typedef float vf4 __attribute__((ext_vector_type(4)));
typedef int   vi4 __attribute__((ext_vector_type(4)));

__global__ __launch_bounds__(256) void CountHistogram_33809982554604_kernel(
    const float* __restrict__ simmat,   // [B,C,Q,D] f32
    const int*   __restrict__ mask,     // [B,Q,D]   int32 (0/1)
    float*       __restrict__ out)      // [B,C,Q,NBINS] f32
{
    __shared__ unsigned int hist[4][WHIST];   // 29,696 B total

    const int bq   = blockIdx.x;          // 0 .. B*Q-1
    const int b    = bq >> 5;             // Q = 32
    const int q    = bq & 31;
    const int wave = threadIdx.x >> 6;    // = c
    const int lane = threadIdx.x & 63;

    unsigned int* __restrict__ h = hist[wave];

    // zero this wave's private columns (wave-private: lockstep, no barrier)
    for (int i = lane; i < WHIST; i += 64) h[i] = 0u;

    const float* __restrict__ srow =
        simmat + (((size_t)b * Cdim + wave) * Qdim + q) * Ddim;
    const int* __restrict__ mrow =
        mask + ((size_t)b * Qdim + q) * Ddim;

    #pragma unroll 8
    for (int j = 0; j < Ddim / 256; ++j) {      // 16 iterations
        const int idx = (j * 64 + lane) * 4;    // element index of this lane's float4
        // simmat: regular cached load (L3 may be primed by the harness's
        // restore-copy of simmat right before the timed launch)
        const vf4 x = *reinterpret_cast<const vf4*>(srow + idx);
        // mask: reused by all 4 waves of this block -> normal cached load
        const vi4 m = *reinterpret_cast<const vi4*>(mrow + idx);

        // (x+1.00001f)*14.0f is bit-identical to ((x+1.00001)/2)*28:
        // /2 is exact, single rounding on the *14 either way.
        int b0 = (int)((x.x + 1.00001f) * 14.0f);
        int b1 = (int)((x.y + 1.00001f) * 14.0f);
        int b2 = (int)((x.z + 1.00001f) * 14.0f);
        int b3 = (int)((x.w + 1.00001f) * 14.0f);
        b0 = min(b0, NBINS - 1);
        b1 = min(b1, NBINS - 1);
        b2 = min(b2, NBINS - 1);
        b3 = min(b3, NBINS - 1);

        // non-atomic privatized RMW: lane owns column `lane`, no aliasing
        h[b0 * NCOPY + lane] += (unsigned int)m.x;
        h[b1 * NCOPY + lane] += (unsigned int)m.y;
        h[b2 * NCOPY + lane] += (unsigned int)m.z;
        h[b3 * NCOPY + lane] += (unsigned int)m.w;
    }

    // reduce 64 private columns per bin; rotate column start so lanes spread
    // across banks each iteration
    if (lane < NBINS) {
        unsigned int sum = 0u;
        #pragma unroll
        for (int i = 0; i < NCOPY; ++i) {
            const int c = (lane + i) & (NCOPY - 1);
            sum += h[lane * NCOPY + c];
        }
        out[(((size_t)b * Cdim + wave) * Qdim + q) * NBINS + lane] = (float)sum;
    }
}

extern "C" void kernel_launch(void* const* d_in, const int* in_sizes, int n_in,
                              void* d_out, int out_size, void* d_ws, size_t ws_size,
                              hipStream_t stream) {
    const float* simmat = (const float*)d_in[0];
    const int*   mask   = (const int*)d_in[1];
    float*       out    = (float*)d_out;

    dim3 grid(Bdim * Qdim);   // 2048 blocks: one per (b,q)
    dim3 block(256);          // 4 waves: one per c
    CountHistogram_33809982554604_kernel<<<grid, block, 0, stream>>>(simmat, mask, out);
}

// Round 8
// 203.942 us; speedup vs baseline: 1.0404x; 1.0404x over previous
//
#include <hip/hip_runtime.h>

// CountHistogram: B=64, C=4, Q=32, D=4096, NBINS=29
// out[b,c,q,bin] = sum_d mask[b,q,d] * (bin == trunc((simmat[b,c,q,d]+1.00001)/2*28))
//
// R7 = revert to R5, the best measured configuration (200.4us).
// Attribution from R0-R6 single-variable tests:
//   - LDS accumulation scheme: NEUTRAL (serialized atomics, replicated
//     atomics, and atomic-free privatized RMW all within 1.5us) -> LDS is
//     off the critical path.
//   - NT on mask: NEUTRAL (R4).
//   - NT on simmat: -11.8us (R6 removed it -> 212.2us; with it -> 200.4us).
//     The 128 MiB read-once simmat stream thrashes L2/L3 when cached,
//     evicting the x4-reused mask rows; NT keeps the stream out.
// Kernel ~= 30us for 161 MiB mandatory traffic (~5.4 TB/s, ~86% of the
// 6.29 TB/s achievable ceiling); dur_us carries ~170us fixed harness reset
// (512 MiB ws poison fill = 78us measured, + d_in restore copies).
//
// Structure: 1 block per (b,q), wave w = channel c; NCOPY=64 lane-private
// histogram columns ([bin][lane] layout, bank=lane&31 -> 2 lanes/bank =
// free tier per m136), plain ds_read+v_add+ds_write (no atomics, no
// barriers - hist is wave-private), nontemporal dwordx4 simmat loads,
// cached mask loads, unroll 8.

constexpr int Bdim  = 64;
constexpr int Cdim  = 4;
constexpr int Qdim  = 32;
constexpr int Ddim  = 4096;
constexpr int NBINS = 29;
constexpr int NCOPY = 64;                 // one private column per lane
constexpr int WHIST = NBINS * NCOPY;      // 1856 words per wave

typedef float vf4 __attribute__((ext_vector_type(4)));
typedef int   vi4 __attribute__((ext_vector_type(4)));

__global__ __launch_bounds__(256) void CountHistogram_33809982554604_kernel(
    const float* __restrict__ simmat,   // [B,C,Q,D] f32
    const int*   __restrict__ mask,     // [B,Q,D]   int32 (0/1)
    float*       __restrict__ out)      // [B,C,Q,NBINS] f32
{
    __shared__ unsigned int hist[4][WHIST];   // 29,696 B total

    const int bq   = blockIdx.x;          // 0 .. B*Q-1
    const int b    = bq >> 5;             // Q = 32
    const int q    = bq & 31;
    const int wave = threadIdx.x >> 6;    // = c
    const int lane = threadIdx.x & 63;

    unsigned int* __restrict__ h = hist[wave];

    // zero this wave's private columns (wave-private: lockstep, no barrier)
    for (int i = lane; i < WHIST; i += 64) h[i] = 0u;

    const float* __restrict__ srow =
        simmat + (((size_t)b * Cdim + wave) * Qdim + q) * Ddim;
    const int* __restrict__ mrow =
        mask + ((size_t)b * Qdim + q) * Ddim;

    #pragma unroll 8
    for (int j = 0; j < Ddim / 256; ++j) {      // 16 iterations
        const int idx = (j * 64 + lane) * 4;    // element index of this lane's float4
        // simmat: read-once stream -> nontemporal (measured -11.8us)
        const vf4 x = __builtin_nontemporal_load(
            reinterpret_cast<const vf4*>(srow + idx));
        // mask: reused by all 4 waves of this block -> normal cached load
        const vi4 m = *reinterpret_cast<const vi4*>(mrow + idx);

        // (x+1.00001f)*14.0f is bit-identical to ((x+1.00001)/2)*28:
        // /2 is exact, single rounding on the *14 either way.
        int b0 = (int)((x.x + 1.00001f) * 14.0f);
        int b1 = (int)((x.y + 1.00001f) * 14.0f);
        int b2 = (int)((x.z + 1.00001f) * 14.0f);
        int b3 = (int)((x.w + 1.00001f) * 14.0f);
        b0 = min(b0, NBINS - 1);
        b1 = min(b1, NBINS - 1);
        b2 = min(b2, NBINS - 1);
        b3 = min(b3, NBINS - 1);

        // non-atomic privatized RMW: lane owns column `lane`, no aliasing
        h[b0 * NCOPY + lane] += (unsigned int)m.x;
        h[b1 * NCOPY + lane] += (unsigned int)m.y;
        h[b2 * NCOPY + lane] += (unsigned int)m.z;
        h[b3 * NCOPY + lane] += (unsigned int)m.w;
    }

    // reduce 64 private columns per bin; rotate column start so lanes spread
    // across banks each iteration
    if (lane < NBINS) {
        unsigned int sum = 0u;
        #pragma unroll
        for (int i = 0; i < NCOPY; ++i) {
            const int c = (lane + i) & (NCOPY - 1);
            sum += h[lane * NCOPY + c];
        }
        out[(((size_t)b * Cdim + wave) * Qdim + q) * NBINS + lane] = (float)sum;
    }
}

extern "C" void kernel_launch(void* const* d_in, const int* in_sizes, int n_in,
                              void* d_out, int out_size, void* d_ws, size_t ws_size,
                              hipStream_t stream) {
    const float* simmat = (const float*)d_in[0];
    const int*   mask   = (const int*)d_in[1];
    float*       out    = (float*)d_out;

    dim3 grid(Bdim * Qdim);   // 2048 blocks: one per (b,q)
    dim3 block(256);          // 4 waves: one per c
    CountHistogram_33809982554604_kernel<<<grid, block, 0, stream>>>(simmat, mask, out);
}